// Round 5
// baseline (269.991 us; speedup 1.0000x reference)
//
#include <hip/hip_runtime.h>
#include <hip/hip_bf16.h>
#include <math.h>

// Problem shape (fixed by setup_inputs):
//   x: [2, 64, 192, 192] fp32, scale=scale2=2 -> sh=sw=384, out: [2,64,384,384] fp32
#define BN  2
#define CN  64
#define HN  192
#define WN  192
#define SH  384
#define SW  384
#define HW  (HN * WN)
#define NPIX (BN * HN * WN)   // 73728

// ---------------------------------------------------------------------------
// Kernel 1 (v4): feat = conv1x1(w_conv, b_conv, [x, sobel_x, sobel_y])
// Block = 64-px row segment x 4 waves (wave = 16 out channels).
// K-loop chunked: stage 8 channels per double-buffered LDS tile -> only 8
// barriers/block (v3 had 64; barrier-latency bound at 80us). Each barrier
// interval: 8 coalesced prefetch loads + 384 FMA/thread (covers latency).
// ---------------------------------------------------------------------------
__global__ __launch_bounds__(256) void feat_kernel(
    const float* __restrict__ x,     // [B,64,H,W]
    const float* __restrict__ wcv,   // [64,192]
    const float* __restrict__ bcv,   // [64]
    float* __restrict__ feat)        // [B,64,H,W]
{
    __shared__ float xs[2][8][3][72];   // 13.8 KB; 72 stride: no pow-2 alias

    const int T = NPIX / 64;                    // 1152 tiles, %8==0
    int B = blockIdx.x;
    int t = (B & 7) * (T >> 3) + (B >> 3);      // XCD band swizzle
    int b  = t / (3 * HN);
    int rr = t - b * (3 * HN);
    int i  = rr / 3;
    int j0 = (rr - i * 3) * 64;

    int tid = threadIdx.x;
    int g = __builtin_amdgcn_readfirstlane(tid >> 6);  // 0..3 channel group
    int lane = tid & 63;
    int o_base = g * 16;

    // staging geometry: element tid of 3x66 halo tile (tid<198 stages)
    int sr  = tid / 66;                 // 0..2
    int scc = tid - sr * 66;            // 0..65
    int gi = i - 1 + sr;
    int gj = j0 - 1 + scc;
    bool stager = (tid < 198);
    bool sok = stager && (gi >= 0) && (gi < HN) && (gj >= 0) && (gj < WN);
    long loff = (long)(b * CN) * HW + (long)gi * WN + gj;  // + c*HW per channel

    float acc[16];
#pragma unroll
    for (int oo = 0; oo < 16; ++oo) acc[oo] = bcv[o_base + oo];

    // prologue: stage chunk 0 (channels 0..7)
    if (stager) {
#pragma unroll
        for (int q = 0; q < 8; ++q)
            xs[0][q][sr][scc] = sok ? x[loff + (long)q * HW] : 0.f;
    }

    for (int ck = 0; ck < 8; ++ck) {
        __syncthreads();
        // prefetch next chunk into the other buffer (no race: different buf,
        // and reads of that buf finished before this barrier)
        if (ck < 7 && stager) {
            int nbuf = (ck + 1) & 1;
#pragma unroll
            for (int q = 0; q < 8; ++q)
                xs[nbuf][q][sr][scc] = sok ? x[loff + (long)((ck + 1) * 8 + q) * HW] : 0.f;
        }
        int p = ck & 1;
        int col = lane + 1;
#pragma unroll
        for (int q = 0; q < 8; ++q) {
            int c = ck * 8 + q;
            float n0 = xs[p][q][0][col - 1], n1 = xs[p][q][0][col], n2 = xs[p][q][0][col + 1];
            float n3 = xs[p][q][1][col - 1], n4 = xs[p][q][1][col], n5 = xs[p][q][1][col + 1];
            float n6 = xs[p][q][2][col - 1], n7 = xs[p][q][2][col], n8 = xs[p][q][2][col + 1];
            float sx = (n2 - n0) + 2.f * (n5 - n3) + (n8 - n6);
            float sy = (n6 - n0) + 2.f * (n7 - n1) + (n8 - n2);
#pragma unroll
            for (int oo = 0; oo < 16; ++oo) {
                const float* wrow = wcv + (o_base + oo) * 192;   // uniform -> s_load
                acc[oo] += wrow[c] * n4 + wrow[64 + c] * sx + wrow[128 + c] * sy;
            }
        }
    }

    size_t ob = (size_t)b * CN * HW + (size_t)i * WN + j0 + lane;
#pragma unroll
    for (int oo = 0; oo < 16; ++oo)
        feat[ob + (size_t)(o_base + oo) * HW] = acc[oo];
}

// ---------------------------------------------------------------------------
// MLP helper: one wave, lane = hidden unit. Returns head partial sums p[6]
// (full sums present in ALL lanes after butterfly).
// ---------------------------------------------------------------------------
__device__ inline void run_mlp(int lane, float in0, float in1, float chv, float cwv,
    const float* __restrict__ wb1, const float* __restrict__ bb1,
    const float* __restrict__ wb2, const float* __restrict__ bb2,
    const float* __restrict__ wr,  const float* __restrict__ wo, float p[6])
{
    float4 w1 = ((const float4*)wb1)[lane];
    float h1 = fmaxf(bb1[lane] + w1.x * in0 + w1.y * in1 + w1.z * chv + w1.w * cwv, 0.f);
    const float4* w2row = (const float4*)(wb2 + lane * 64);
    float acc = bb2[lane];
#pragma unroll
    for (int q = 0; q < 16; ++q) {
        float4 wv = w2row[q];
        acc += wv.x * __shfl(h1, q * 4 + 0)
             + wv.y * __shfl(h1, q * 4 + 1)
             + wv.z * __shfl(h1, q * 4 + 2)
             + wv.w * __shfl(h1, q * 4 + 3);
    }
    float h2 = fmaxf(acc, 0.f);
#pragma unroll
    for (int e = 0; e < 4; ++e) p[e] = wr[e * 64 + lane] * h2;
#pragma unroll
    for (int e = 0; e < 2; ++e) p[4 + e] = wo[e * 64 + lane] * h2;
#pragma unroll
    for (int m = 1; m < 64; m <<= 1) {
#pragma unroll
        for (int e = 0; e < 6; ++e) p[e] += __shfl_xor(p[e], m);
    }
}

// ---------------------------------------------------------------------------
// Kernel 2 (v4): periodic routing/offset table.
// tblEntry[entry][8] = {re[4], offx, offy, pad, pad}.
// Fast mode (sc2==2, sc<=16): wave pi computes BOTH parity classes and emits
// mixed expert matrices as (avg,diff) pairs at tblMix[pi][2048]:
//   [0:512)    wc_avg[k][c]   [512:1024)  wc_diff[k][c]
//   [1024:1536) we_avg[c][k]  [1536:2048) we_diff[c][k]
// ---------------------------------------------------------------------------
__global__ __launch_bounds__(256) void mlp_table_kernel(
    const float* __restrict__ wb1, const float* __restrict__ bb1,
    const float* __restrict__ wb2, const float* __restrict__ bb2,
    const float* __restrict__ wr,  const float* __restrict__ br,
    const float* __restrict__ wo,  const float* __restrict__ bo,
    const float* __restrict__ wce, const float* __restrict__ wee,
    const int* __restrict__ scale_p, const int* __restrict__ scale2_p,
    float* __restrict__ tblEntry, float* __restrict__ tblMix)
{
    int sc = scale_p[0], sc2 = scale2_p[0];
    int w = (blockIdx.x * 256 + threadIdx.x) >> 6;
    int lane = threadIdx.x & 63;
    float scale = (float)sc, scale2 = (float)sc2;
    float in0 = 1.f / scale2, in1 = 1.f / scale;
    bool fast = (sc2 == 2 && sc <= 16);

    if (fast) {
        if (w >= sc) return;
        int pi = w;
        float ih = (pi + 0.5f) / scale;
        float chv = ih - floorf(ih + 0.001f) - 0.5f;
        float p0[6], p1[6];
        {
            float iw = 0.5f / scale2;
            float cwv = iw - floorf(iw + 0.001f) - 0.5f;
            run_mlp(lane, in0, in1, chv, cwv, wb1, bb1, wb2, bb2, wr, wo, p0);
        }
        {
            float iw = 1.5f / scale2;
            float cwv = iw - floorf(iw + 0.001f) - 0.5f;
            run_mlp(lane, in0, in1, chv, cwv, wb1, bb1, wb2, bb2, wr, wo, p1);
        }
        float reE[4], reO[4];
#pragma unroll
        for (int e = 0; e < 4; ++e) {
            reE[e] = 1.f / (1.f + expf(-(p0[e] + br[e])));
            reO[e] = 1.f / (1.f + expf(-(p1[e] + br[e])));
        }
        if (lane == 0) {
            float* t0 = tblEntry + (pi * 2 + 0) * 8;
            float* t1 = tblEntry + (pi * 2 + 1) * 8;
#pragma unroll
            for (int e = 0; e < 4; ++e) { t0[e] = reE[e]; t1[e] = reO[e]; }
            t0[4] = p0[4] + bo[0]; t0[5] = p0[5] + bo[1];
            t1[4] = p1[4] + bo[0]; t1[5] = p1[5] + bo[1];
        }
        float* mp = tblMix + pi * 2048;
        for (int idx = lane; idx < 512; idx += 64) {
            float cE = reE[0] * wce[idx]        + reE[1] * wce[512 + idx]
                     + reE[2] * wce[1024 + idx] + reE[3] * wce[1536 + idx];
            float cO = reO[0] * wce[idx]        + reO[1] * wce[512 + idx]
                     + reO[2] * wce[1024 + idx] + reO[3] * wce[1536 + idx];
            mp[idx]       = 0.5f * (cE + cO);
            mp[512 + idx] = 0.5f * (cE - cO);
            float eE = reE[0] * wee[idx]        + reE[1] * wee[512 + idx]
                     + reE[2] * wee[1024 + idx] + reE[3] * wee[1536 + idx];
            float eO = reO[0] * wee[idx]        + reO[1] * wee[512 + idx]
                     + reO[2] * wee[1024 + idx] + reO[3] * wee[1536 + idx];
            mp[1024 + idx] = 0.5f * (eE + eO);
            mp[1536 + idx] = 0.5f * (eE - eO);
        }
    } else {
        if (w >= sc * sc2) return;
        int pi = w / sc2, pj = w - pi * sc2;
        float ih = (pi + 0.5f) / scale;
        float chv = ih - floorf(ih + 0.001f) - 0.5f;
        float iw = (pj + 0.5f) / scale2;
        float cwv = iw - floorf(iw + 0.001f) - 0.5f;
        float p[6];
        run_mlp(lane, in0, in1, chv, cwv, wb1, bb1, wb2, bb2, wr, wo, p);
        if (lane == 0) {
            float* tp = tblEntry + w * 8;
#pragma unroll
            for (int e = 0; e < 4; ++e) tp[e] = 1.f / (1.f + expf(-(p[e] + br[e])));
            tp[4] = p[4] + bo[0];
            tp[5] = p[5] + bo[1];
        }
    }
}

// ---------------------------------------------------------------------------
// Kernel 3 (v3): bilinear gather + expert mix + residual.
// Block = 64 px row segment x 4 waves (wave = 16 channels).
// XCD band swizzle for feat L2 locality. Fast path (sc2==2): wave-uniform
// (avg,diff) mixed weights + per-lane parity sign. Generic path kept.
// ---------------------------------------------------------------------------
__global__ __launch_bounds__(256) void out_kernel(
    const float* __restrict__ feat,      // [B,64,H,W]
    const float* __restrict__ tblEntry,  // [256][8]
    const float* __restrict__ tblMix,    // [16][2048]
    const float* __restrict__ wce,       // [4,8,64]
    const float* __restrict__ wee,       // [4,64,8]
    const int* __restrict__ scale_p, const int* __restrict__ scale2_p,
    float* __restrict__ out)             // [B,64,SH,SW]
{
    __shared__ float midp[4 * 64 * 9];

    int Bk = blockIdx.x;
    int T = gridDim.x;                           // 4608, %8==0
    int t = ((T & 7) == 0) ? ((Bk & 7) * (T >> 3) + (Bk >> 3)) : Bk;

    int tid = threadIdx.x;
    int g = __builtin_amdgcn_readfirstlane(tid >> 6);
    int lane = tid & 63;
    int pix0 = t * 64;
    int b = pix0 / (SH * SW);
    int r0 = pix0 - b * SH * SW;
    int i = r0 / SW;
    int j0 = r0 - i * SW;
    int j = j0 + lane;
    int r = r0 + lane;

    int sc = scale_p[0], sc2 = scale2_p[0];
    float scale = (float)sc, scale2 = (float)sc2;
    int pi = i - (i / sc) * sc;          // wave-uniform
    int pj = j - (j / sc2) * sc2;        // per-lane
    int entry = pi * sc2 + pj;
    float offx = tblEntry[entry * 8 + 4];
    float offy = tblEntry[entry * 8 + 5];

    const float inv_wm1 = 2.f / (float)(WN - 1);
    const float inv_hm1 = 2.f / (float)(HN - 1);
    float gx = ((j + 0.5f) / scale2 - 0.5f) * inv_wm1 - 1.f + offx * inv_wm1;
    float gy = ((i + 0.5f) / scale  - 0.5f) * inv_hm1 - 1.f + offy * inv_hm1;

    float ix = ((gx + 1.f) * WN - 1.f) * 0.5f;
    float iy = ((gy + 1.f) * HN - 1.f) * 0.5f;
    float fx0 = floorf(ix), fy0 = floorf(iy);
    int x0 = (int)fx0, y0 = (int)fy0;
    float wx1 = ix - fx0, wx0 = 1.f - wx1;
    float wy1 = iy - fy0, wy0 = 1.f - wy1;

    bool vx0 = (x0 >= 0) && (x0 <= WN - 1);
    bool vx1 = (x0 + 1 >= 0) && (x0 + 1 <= WN - 1);
    bool vy0 = (y0 >= 0) && (y0 <= HN - 1);
    bool vy1 = (y0 + 1 >= 0) && (y0 + 1 <= HN - 1);
    bool v00 = vx0 && vy0, v10 = vx1 && vy0, v01 = vx0 && vy1, v11 = vx1 && vy1;
    float w00 = wx0 * wy0, w10 = wx1 * wy0, w01 = wx0 * wy1, w11 = wx1 * wy1;

    int i00 = y0 * WN + x0;
    int i10 = i00 + 1;
    int i01 = i00 + WN;
    int i11 = i01 + 1;

    const float* fb = feat + (size_t)b * CN * HW;

    float f0[16];
#pragma unroll
    for (int cc = 0; cc < 16; ++cc) {
        const float* fc = fb + (size_t)(g * 16 + cc) * HW;
        float a  = v00 ? fc[i00] : 0.f;
        float bq = v10 ? fc[i10] : 0.f;
        float cq = v01 ? fc[i01] : 0.f;
        float dq = v11 ? fc[i11] : 0.f;
        f0[cc] = a * w00 + bq * w10 + cq * w01 + dq * w11;
    }

    bool fast = (sc2 == 2 && sc <= 16);
    if (fast) {
        float sgn = (pj == 0) ? 1.f : -1.f;
        const float* mp = tblMix + pi * 2048;    // uniform base -> s_load weights
#pragma unroll
        for (int k = 0; k < 8; ++k) {
            const float* wa = mp + k * 64 + g * 16;
            const float* wd = mp + 512 + k * 64 + g * 16;
            float dA = 0.f, dB = 0.f;
#pragma unroll
            for (int cc = 0; cc < 16; ++cc) { dA += wa[cc] * f0[cc]; dB += wd[cc] * f0[cc]; }
            midp[(g * 64 + lane) * 9 + k] = fmaf(sgn, dB, dA);
        }
        __syncthreads();
        float mid[8];
#pragma unroll
        for (int k = 0; k < 8; ++k)
            mid[k] = midp[(0 * 64 + lane) * 9 + k] + midp[(1 * 64 + lane) * 9 + k]
                   + midp[(2 * 64 + lane) * 9 + k] + midp[(3 * 64 + lane) * 9 + k];
#pragma unroll
        for (int cc = 0; cc < 16; ++cc) {
            int c = g * 16 + cc;
            const float* wa = mp + 1024 + c * 8;
            const float* wd = mp + 1536 + c * 8;
            float vA = 0.f, vB = 0.f;
#pragma unroll
            for (int k = 0; k < 8; ++k) { vA += wa[k] * mid[k]; vB += wd[k] * mid[k]; }
            out[(size_t)(b * CN + c) * SH * SW + r] = f0[cc] + fmaf(sgn, vB, vA);
        }
    } else {
        float4 rw = *(const float4*)(tblEntry + entry * 8);
        float re[4] = {rw.x, rw.y, rw.z, rw.w};
        float part[4][8];
#pragma unroll
        for (int e = 0; e < 4; ++e) {
#pragma unroll
            for (int k = 0; k < 8; ++k) {
                const float* wrow = wce + (e * 8 + k) * 64 + g * 16;
                float d = 0.f;
#pragma unroll
                for (int cc = 0; cc < 16; ++cc) d += wrow[cc] * f0[cc];
                part[e][k] = d;
            }
        }
#pragma unroll
        for (int k = 0; k < 8; ++k) {
            float m = re[0] * part[0][k] + re[1] * part[1][k]
                    + re[2] * part[2][k] + re[3] * part[3][k];
            midp[(g * 64 + lane) * 9 + k] = m;
        }
        __syncthreads();
        float mid[8];
#pragma unroll
        for (int k = 0; k < 8; ++k)
            mid[k] = midp[(0 * 64 + lane) * 9 + k] + midp[(1 * 64 + lane) * 9 + k]
                   + midp[(2 * 64 + lane) * 9 + k] + midp[(3 * 64 + lane) * 9 + k];
#pragma unroll
        for (int cc = 0; cc < 16; ++cc) {
            int c = g * 16 + cc;
            float v = f0[cc];
#pragma unroll
            for (int e = 0; e < 4; ++e) {
                const float* wrow = wee + (e * 64 + c) * 8;
                float d = 0.f;
#pragma unroll
                for (int k = 0; k < 8; ++k) d += wrow[k] * mid[k];
                v += re[e] * d;
            }
            out[(size_t)(b * CN + c) * SH * SW + r] = v;
        }
    }
}

extern "C" void kernel_launch(void* const* d_in, const int* in_sizes, int n_in,
                              void* d_out, int out_size, void* d_ws, size_t ws_size,
                              hipStream_t stream) {
    const float* x    = (const float*)d_in[0];
    const float* wce  = (const float*)d_in[1];
    const float* wee  = (const float*)d_in[2];
    const float* wb1  = (const float*)d_in[3];
    const float* bb1  = (const float*)d_in[4];
    const float* wb2  = (const float*)d_in[5];
    const float* bb2  = (const float*)d_in[6];
    const float* wr   = (const float*)d_in[7];
    const float* br   = (const float*)d_in[8];
    const float* wo   = (const float*)d_in[9];
    const float* bo   = (const float*)d_in[10];
    const float* wcv  = (const float*)d_in[11];
    const float* bcv  = (const float*)d_in[12];
    const int*   scale  = (const int*)d_in[13];
    const int*   scale2 = (const int*)d_in[14];
    float* out = (float*)d_out;

    float* feat     = (float*)d_ws;                       // BN*CN*HW floats
    float* tblEntry = feat + (size_t)BN * CN * HW;        // 256*8 floats
    float* tblMix   = tblEntry + 256 * 8;                 // 16*2048 floats

    feat_kernel<<<NPIX / 64, 256, 0, stream>>>(x, wcv, bcv, feat);
    mlp_table_kernel<<<64, 256, 0, stream>>>(wb1, bb1, wb2, bb2, wr, br, wo, bo,
                                             wce, wee, scale, scale2,
                                             tblEntry, tblMix);
    out_kernel<<<BN * SH * SW / 64, 256, 0, stream>>>(feat, tblEntry, tblMix,
                                                      wce, wee, scale, scale2, out);
}

// Round 6
// 199.419 us; speedup vs baseline: 1.3539x; 1.3539x over previous
//
#include <hip/hip_runtime.h>
#include <hip/hip_bf16.h>
#include <math.h>

// Problem shape (fixed by setup_inputs):
//   x: [2, 64, 192, 192] fp32, scale=scale2=2 -> sh=sw=384, out: [2,64,384,384] fp32
#define BN  2
#define CN  64
#define HN  192
#define WN  192
#define SH  384
#define SW  384
#define HW  (HN * WN)
#define NPIX (BN * HN * WN)   // 73728

// ---------------------------------------------------------------------------
// Kernel 1 (v5): feat = conv1x1(w_conv, b_conv, [x, sobel_x, sobel_y])
// One thread per (pixel, 16-out-channel group); wave = 64 consecutive columns.
// Per input channel: 3 own-column loads (row-masked) + 6 side taps via
// __shfl_up/down + lanes 0/63 patched from wave-UNIFORM halo columns
// (s_load). No LDS, no barriers -> compiler pipelines the channel loop.
// Weight reads: 48 uniform s_loads live per channel (R3-proven scalarization;
// v4's 8x-unrolled 384-scalar working set de-scalarized and regressed).
// ---------------------------------------------------------------------------
__global__ __launch_bounds__(256) void feat_kernel(
    const float* __restrict__ x,     // [B,64,H,W]
    const float* __restrict__ wcv,   // [64,192]
    const float* __restrict__ bcv,   // [64]
    float* __restrict__ feat)        // [B,64,H,W]
{
    int idx = blockIdx.x * 256 + threadIdx.x;          // 4*NPIX threads exactly
    int group = __builtin_amdgcn_readfirstlane(idx / NPIX);  // 0..3 (block-uniform)
    int pix = idx - group * NPIX;
    int b = pix / HW;
    int r = pix - b * HW;
    int i = r / WN;
    int j = r - i * WN;
    int lane = threadIdx.x & 63;
    int j0 = __builtin_amdgcn_readfirstlane(j - lane);  // wave-uniform col base
    int o_base = group * 16;

    bool ok_t = (i > 0), ok_b = (i < HN - 1);           // wave-uniform
    bool okL = (j0 > 0), okR = (j0 + 64 < WN);          // wave-uniform
    float mt = ok_t ? 1.f : 0.f, mb = ok_b ? 1.f : 0.f;
    int rT = ok_t ? i - 1 : i;       // clamped rows (loads always in-bounds)
    int rB = ok_b ? i + 1 : i;
    int jL = okL ? j0 - 1 : j0;      // clamped halo columns
    int jR = okR ? j0 + 64 : j0;
    float mLt = okL ? mt : 0.f, mLm = okL ? 1.f : 0.f, mLb = okL ? mb : 0.f;
    float mRt = okR ? mt : 0.f, mRm = okR ? 1.f : 0.f, mRb = okR ? mb : 0.f;

    bool isL = (lane == 0), isR = (lane == 63);

    const float* xb = x + (size_t)b * CN * HW;
    size_t oT = (size_t)rT * WN, oM = (size_t)i * WN, oB = (size_t)rB * WN;

    float acc[16];
#pragma unroll
    for (int oo = 0; oo < 16; ++oo) acc[oo] = bcv[o_base + oo];

    for (int c = 0; c < CN; ++c) {
        const float* xc = xb + (size_t)c * HW;
        // own column, 3 rows (masked)
        float t  = xc[oT + j] * mt;
        float m  = xc[oM + j];
        float bt = xc[oB + j] * mb;
        // wave-uniform halo columns -> s_load
        float hLt = xc[oT + jL] * mLt;
        float hLm = xc[oM + jL] * mLm;
        float hLb = xc[oB + jL] * mLb;
        float hRt = xc[oT + jR] * mRt;
        float hRm = xc[oM + jR] * mRm;
        float hRb = xc[oB + jR] * mRb;
        // side taps from neighbor lanes
        float tl = __shfl_up(t, 1),  ml_ = __shfl_up(m, 1),  bl = __shfl_up(bt, 1);
        float tr = __shfl_down(t, 1), mr_ = __shfl_down(m, 1), br_ = __shfl_down(bt, 1);
        float n0 = isL ? hLt : tl;
        float n3 = isL ? hLm : ml_;
        float n6 = isL ? hLb : bl;
        float n2 = isR ? hRt : tr;
        float n5 = isR ? hRm : mr_;
        float n8 = isR ? hRb : br_;
        // sobel (n1=t, n4=m, n7=bt)
        float sx = (n2 - n0) + 2.f * (n5 - n3) + (n8 - n6);
        float sy = (n6 - n0) + 2.f * (bt - t) + (n8 - n2);
#pragma unroll
        for (int oo = 0; oo < 16; ++oo) {
            const float* wrow = wcv + (o_base + oo) * 192;   // uniform -> s_load
            acc[oo] += wrow[c] * m + wrow[64 + c] * sx + wrow[128 + c] * sy;
        }
    }

    size_t ob = (size_t)b * CN * HW + (size_t)i * WN + j;
#pragma unroll
    for (int oo = 0; oo < 16; ++oo)
        feat[ob + (size_t)(o_base + oo) * HW] = acc[oo];
}

// ---------------------------------------------------------------------------
// MLP helper: one wave, lane = hidden unit. Returns head partial sums p[6]
// (full sums present in ALL lanes after butterfly).
// ---------------------------------------------------------------------------
__device__ inline void run_mlp(int lane, float in0, float in1, float chv, float cwv,
    const float* __restrict__ wb1, const float* __restrict__ bb1,
    const float* __restrict__ wb2, const float* __restrict__ bb2,
    const float* __restrict__ wr,  const float* __restrict__ wo, float p[6])
{
    float4 w1 = ((const float4*)wb1)[lane];
    float h1 = fmaxf(bb1[lane] + w1.x * in0 + w1.y * in1 + w1.z * chv + w1.w * cwv, 0.f);
    const float4* w2row = (const float4*)(wb2 + lane * 64);
    float acc = bb2[lane];
#pragma unroll
    for (int q = 0; q < 16; ++q) {
        float4 wv = w2row[q];
        acc += wv.x * __shfl(h1, q * 4 + 0)
             + wv.y * __shfl(h1, q * 4 + 1)
             + wv.z * __shfl(h1, q * 4 + 2)
             + wv.w * __shfl(h1, q * 4 + 3);
    }
    float h2 = fmaxf(acc, 0.f);
#pragma unroll
    for (int e = 0; e < 4; ++e) p[e] = wr[e * 64 + lane] * h2;
#pragma unroll
    for (int e = 0; e < 2; ++e) p[4 + e] = wo[e * 64 + lane] * h2;
#pragma unroll
    for (int m = 1; m < 64; m <<= 1) {
#pragma unroll
        for (int e = 0; e < 6; ++e) p[e] += __shfl_xor(p[e], m);
    }
}

// ---------------------------------------------------------------------------
// Kernel 2 (v4): periodic routing/offset table.
// tblEntry[entry][8] = {re[4], offx, offy, pad, pad}.
// Fast mode (sc2==2, sc<=16): wave pi computes BOTH parity classes and emits
// mixed expert matrices as (avg,diff) pairs at tblMix[pi][2048].
// ---------------------------------------------------------------------------
__global__ __launch_bounds__(256) void mlp_table_kernel(
    const float* __restrict__ wb1, const float* __restrict__ bb1,
    const float* __restrict__ wb2, const float* __restrict__ bb2,
    const float* __restrict__ wr,  const float* __restrict__ br,
    const float* __restrict__ wo,  const float* __restrict__ bo,
    const float* __restrict__ wce, const float* __restrict__ wee,
    const int* __restrict__ scale_p, const int* __restrict__ scale2_p,
    float* __restrict__ tblEntry, float* __restrict__ tblMix)
{
    int sc = scale_p[0], sc2 = scale2_p[0];
    int w = (blockIdx.x * 256 + threadIdx.x) >> 6;
    int lane = threadIdx.x & 63;
    float scale = (float)sc, scale2 = (float)sc2;
    float in0 = 1.f / scale2, in1 = 1.f / scale;
    bool fast = (sc2 == 2 && sc <= 16);

    if (fast) {
        if (w >= sc) return;
        int pi = w;
        float ih = (pi + 0.5f) / scale;
        float chv = ih - floorf(ih + 0.001f) - 0.5f;
        float p0[6], p1[6];
        {
            float iw = 0.5f / scale2;
            float cwv = iw - floorf(iw + 0.001f) - 0.5f;
            run_mlp(lane, in0, in1, chv, cwv, wb1, bb1, wb2, bb2, wr, wo, p0);
        }
        {
            float iw = 1.5f / scale2;
            float cwv = iw - floorf(iw + 0.001f) - 0.5f;
            run_mlp(lane, in0, in1, chv, cwv, wb1, bb1, wb2, bb2, wr, wo, p1);
        }
        float reE[4], reO[4];
#pragma unroll
        for (int e = 0; e < 4; ++e) {
            reE[e] = 1.f / (1.f + expf(-(p0[e] + br[e])));
            reO[e] = 1.f / (1.f + expf(-(p1[e] + br[e])));
        }
        if (lane == 0) {
            float* t0 = tblEntry + (pi * 2 + 0) * 8;
            float* t1 = tblEntry + (pi * 2 + 1) * 8;
#pragma unroll
            for (int e = 0; e < 4; ++e) { t0[e] = reE[e]; t1[e] = reO[e]; }
            t0[4] = p0[4] + bo[0]; t0[5] = p0[5] + bo[1];
            t1[4] = p1[4] + bo[0]; t1[5] = p1[5] + bo[1];
        }
        float* mp = tblMix + pi * 2048;
        for (int idx = lane; idx < 512; idx += 64) {
            float cE = reE[0] * wce[idx]        + reE[1] * wce[512 + idx]
                     + reE[2] * wce[1024 + idx] + reE[3] * wce[1536 + idx];
            float cO = reO[0] * wce[idx]        + reO[1] * wce[512 + idx]
                     + reO[2] * wce[1024 + idx] + reO[3] * wce[1536 + idx];
            mp[idx]       = 0.5f * (cE + cO);
            mp[512 + idx] = 0.5f * (cE - cO);
            float eE = reE[0] * wee[idx]        + reE[1] * wee[512 + idx]
                     + reE[2] * wee[1024 + idx] + reE[3] * wee[1536 + idx];
            float eO = reO[0] * wee[idx]        + reO[1] * wee[512 + idx]
                     + reO[2] * wee[1024 + idx] + reO[3] * wee[1536 + idx];
            mp[1024 + idx] = 0.5f * (eE + eO);
            mp[1536 + idx] = 0.5f * (eE - eO);
        }
    } else {
        if (w >= sc * sc2) return;
        int pi = w / sc2, pj = w - pi * sc2;
        float ih = (pi + 0.5f) / scale;
        float chv = ih - floorf(ih + 0.001f) - 0.5f;
        float iw = (pj + 0.5f) / scale2;
        float cwv = iw - floorf(iw + 0.001f) - 0.5f;
        float p[6];
        run_mlp(lane, in0, in1, chv, cwv, wb1, bb1, wb2, bb2, wr, wo, p);
        if (lane == 0) {
            float* tp = tblEntry + w * 8;
#pragma unroll
            for (int e = 0; e < 4; ++e) tp[e] = 1.f / (1.f + expf(-(p[e] + br[e])));
            tp[4] = p[4] + bo[0];
            tp[5] = p[5] + bo[1];
        }
    }
}

// ---------------------------------------------------------------------------
// Kernel 3 (v3): bilinear gather + expert mix + residual.
// Block = 64 px row segment x 4 waves (wave = 16 channels).
// XCD band swizzle for feat L2 locality. Fast path (sc2==2): wave-uniform
// (avg,diff) mixed weights + per-lane parity sign. Generic path kept.
// ---------------------------------------------------------------------------
__global__ __launch_bounds__(256) void out_kernel(
    const float* __restrict__ feat,      // [B,64,H,W]
    const float* __restrict__ tblEntry,  // [256][8]
    const float* __restrict__ tblMix,    // [16][2048]
    const float* __restrict__ wce,       // [4,8,64]
    const float* __restrict__ wee,       // [4,64,8]
    const int* __restrict__ scale_p, const int* __restrict__ scale2_p,
    float* __restrict__ out)             // [B,64,SH,SW]
{
    __shared__ float midp[4 * 64 * 9];

    int Bk = blockIdx.x;
    int T = gridDim.x;                           // 4608, %8==0
    int t = ((T & 7) == 0) ? ((Bk & 7) * (T >> 3) + (Bk >> 3)) : Bk;

    int tid = threadIdx.x;
    int g = __builtin_amdgcn_readfirstlane(tid >> 6);
    int lane = tid & 63;
    int pix0 = t * 64;
    int b = pix0 / (SH * SW);
    int r0 = pix0 - b * SH * SW;
    int i = r0 / SW;
    int j0 = r0 - i * SW;
    int j = j0 + lane;
    int r = r0 + lane;

    int sc = scale_p[0], sc2 = scale2_p[0];
    float scale = (float)sc, scale2 = (float)sc2;
    int pi = i - (i / sc) * sc;          // wave-uniform
    int pj = j - (j / sc2) * sc2;        // per-lane
    int entry = pi * sc2 + pj;
    float offx = tblEntry[entry * 8 + 4];
    float offy = tblEntry[entry * 8 + 5];

    const float inv_wm1 = 2.f / (float)(WN - 1);
    const float inv_hm1 = 2.f / (float)(HN - 1);
    float gx = ((j + 0.5f) / scale2 - 0.5f) * inv_wm1 - 1.f + offx * inv_wm1;
    float gy = ((i + 0.5f) / scale  - 0.5f) * inv_hm1 - 1.f + offy * inv_hm1;

    float ix = ((gx + 1.f) * WN - 1.f) * 0.5f;
    float iy = ((gy + 1.f) * HN - 1.f) * 0.5f;
    float fx0 = floorf(ix), fy0 = floorf(iy);
    int x0 = (int)fx0, y0 = (int)fy0;
    float wx1 = ix - fx0, wx0 = 1.f - wx1;
    float wy1 = iy - fy0, wy0 = 1.f - wy1;

    bool vx0 = (x0 >= 0) && (x0 <= WN - 1);
    bool vx1 = (x0 + 1 >= 0) && (x0 + 1 <= WN - 1);
    bool vy0 = (y0 >= 0) && (y0 <= HN - 1);
    bool vy1 = (y0 + 1 >= 0) && (y0 + 1 <= HN - 1);
    bool v00 = vx0 && vy0, v10 = vx1 && vy0, v01 = vx0 && vy1, v11 = vx1 && vy1;
    float w00 = wx0 * wy0, w10 = wx1 * wy0, w01 = wx0 * wy1, w11 = wx1 * wy1;

    int i00 = y0 * WN + x0;
    int i10 = i00 + 1;
    int i01 = i00 + WN;
    int i11 = i01 + 1;

    const float* fb = feat + (size_t)b * CN * HW;

    float f0[16];
#pragma unroll
    for (int cc = 0; cc < 16; ++cc) {
        const float* fc = fb + (size_t)(g * 16 + cc) * HW;
        float a  = v00 ? fc[i00] : 0.f;
        float bq = v10 ? fc[i10] : 0.f;
        float cq = v01 ? fc[i01] : 0.f;
        float dq = v11 ? fc[i11] : 0.f;
        f0[cc] = a * w00 + bq * w10 + cq * w01 + dq * w11;
    }

    bool fast = (sc2 == 2 && sc <= 16);
    if (fast) {
        float sgn = (pj == 0) ? 1.f : -1.f;
        const float* mp = tblMix + pi * 2048;    // uniform base -> s_load weights
#pragma unroll
        for (int k = 0; k < 8; ++k) {
            const float* wa = mp + k * 64 + g * 16;
            const float* wd = mp + 512 + k * 64 + g * 16;
            float dA = 0.f, dB = 0.f;
#pragma unroll
            for (int cc = 0; cc < 16; ++cc) { dA += wa[cc] * f0[cc]; dB += wd[cc] * f0[cc]; }
            midp[(g * 64 + lane) * 9 + k] = fmaf(sgn, dB, dA);
        }
        __syncthreads();
        float mid[8];
#pragma unroll
        for (int k = 0; k < 8; ++k)
            mid[k] = midp[(0 * 64 + lane) * 9 + k] + midp[(1 * 64 + lane) * 9 + k]
                   + midp[(2 * 64 + lane) * 9 + k] + midp[(3 * 64 + lane) * 9 + k];
#pragma unroll
        for (int cc = 0; cc < 16; ++cc) {
            int c = g * 16 + cc;
            const float* wa = mp + 1024 + c * 8;
            const float* wd = mp + 1536 + c * 8;
            float vA = 0.f, vB = 0.f;
#pragma unroll
            for (int k = 0; k < 8; ++k) { vA += wa[k] * mid[k]; vB += wd[k] * mid[k]; }
            out[(size_t)(b * CN + c) * SH * SW + r] = f0[cc] + fmaf(sgn, vB, vA);
        }
    } else {
        float4 rw = *(const float4*)(tblEntry + entry * 8);
        float re[4] = {rw.x, rw.y, rw.z, rw.w};
        float part[4][8];
#pragma unroll
        for (int e = 0; e < 4; ++e) {
#pragma unroll
            for (int k = 0; k < 8; ++k) {
                const float* wrow = wce + (e * 8 + k) * 64 + g * 16;
                float d = 0.f;
#pragma unroll
                for (int cc = 0; cc < 16; ++cc) d += wrow[cc] * f0[cc];
                part[e][k] = d;
            }
        }
#pragma unroll
        for (int k = 0; k < 8; ++k) {
            float m = re[0] * part[0][k] + re[1] * part[1][k]
                    + re[2] * part[2][k] + re[3] * part[3][k];
            midp[(g * 64 + lane) * 9 + k] = m;
        }
        __syncthreads();
        float mid[8];
#pragma unroll
        for (int k = 0; k < 8; ++k)
            mid[k] = midp[(0 * 64 + lane) * 9 + k] + midp[(1 * 64 + lane) * 9 + k]
                   + midp[(2 * 64 + lane) * 9 + k] + midp[(3 * 64 + lane) * 9 + k];
#pragma unroll
        for (int cc = 0; cc < 16; ++cc) {
            int c = g * 16 + cc;
            float v = f0[cc];
#pragma unroll
            for (int e = 0; e < 4; ++e) {
                const float* wrow = wee + (e * 64 + c) * 8;
                float d = 0.f;
#pragma unroll
                for (int k = 0; k < 8; ++k) d += wrow[k] * mid[k];
                v += re[e] * d;
            }
            out[(size_t)(b * CN + c) * SH * SW + r] = v;
        }
    }
}

extern "C" void kernel_launch(void* const* d_in, const int* in_sizes, int n_in,
                              void* d_out, int out_size, void* d_ws, size_t ws_size,
                              hipStream_t stream) {
    const float* x    = (const float*)d_in[0];
    const float* wce  = (const float*)d_in[1];
    const float* wee  = (const float*)d_in[2];
    const float* wb1  = (const float*)d_in[3];
    const float* bb1  = (const float*)d_in[4];
    const float* wb2  = (const float*)d_in[5];
    const float* bb2  = (const float*)d_in[6];
    const float* wr   = (const float*)d_in[7];
    const float* br   = (const float*)d_in[8];
    const float* wo   = (const float*)d_in[9];
    const float* bo   = (const float*)d_in[10];
    const float* wcv  = (const float*)d_in[11];
    const float* bcv  = (const float*)d_in[12];
    const int*   scale  = (const int*)d_in[13];
    const int*   scale2 = (const int*)d_in[14];
    float* out = (float*)d_out;

    float* feat     = (float*)d_ws;                       // BN*CN*HW floats
    float* tblEntry = feat + (size_t)BN * CN * HW;        // 256*8 floats
    float* tblMix   = tblEntry + 256 * 8;                 // 16*2048 floats

    feat_kernel<<<4 * NPIX / 256, 256, 0, stream>>>(x, wcv, bcv, feat);
    mlp_table_kernel<<<64, 256, 0, stream>>>(wb1, bb1, wb2, bb2, wr, br, wo, bo,
                                             wce, wee, scale, scale2,
                                             tblEntry, tblMix);
    out_kernel<<<BN * SH * SW / 64, 256, 0, stream>>>(feat, tblEntry, tblMix,
                                                      wce, wee, scale, scale2, out);
}